// Round 2
// baseline (403.926 us; speedup 1.0000x reference)
//
#include <hip/hip_runtime.h>
#include <hip/hip_bf16.h>

typedef unsigned short u16;
typedef __bf16 bf16x8 __attribute__((ext_vector_type(8)));
typedef float f32x4 __attribute__((ext_vector_type(4)));
typedef unsigned short u16x8 __attribute__((ext_vector_type(8)));
typedef unsigned short u16x4 __attribute__((ext_vector_type(4)));

__device__ __forceinline__ u16 f2bf(float f) {
  unsigned u = __builtin_bit_cast(unsigned, f);
  u += 0x7FFFu + ((u >> 16) & 1u);
  return (u16)(u >> 16);
}

// async global->LDS, 16B per lane; lds base must be wave-uniform
#define GLD16(gp, lp)                                                          \
  __builtin_amdgcn_global_load_lds(                                            \
      (const __attribute__((address_space(1))) void*)(gp),                     \
      (__attribute__((address_space(3))) void*)(lp), 16, 0, 0)

// ---------------- cast kernels ----------------

__global__ __launch_bounds__(256) void cast_f32_bf16(
    const float* __restrict__ in, u16* __restrict__ out, int n4) {
  int i = blockIdx.x * 256 + threadIdx.x;
  if (i >= n4) return;
  float4 v = ((const float4*)in)[i];
  u16x4 o = {f2bf(v.x), f2bf(v.y), f2bf(v.z), f2bf(v.w)};
  *(u16x4*)(out + (size_t)i * 4) = o;
}

// out[c][r] = (bf16) in[r][c];  in: R x C f32, out: C x R bf16
__global__ __launch_bounds__(256) void transpose_cast(
    const float* __restrict__ in, u16* __restrict__ out, int R, int C) {
  __shared__ float t[32][33];
  int c0 = blockIdx.x * 32, r0 = blockIdx.y * 32;
  int tx = threadIdx.x, ty = threadIdx.y;
#pragma unroll
  for (int k = 0; k < 4; ++k)
    t[ty + 8 * k][tx] = in[(size_t)(r0 + ty + 8 * k) * C + c0 + tx];
  __syncthreads();
#pragma unroll
  for (int k = 0; k < 4; ++k)
    out[(size_t)(c0 + ty + 8 * k) * R + r0 + tx] = f2bf(t[tx][ty + 8 * k]);
}

// ---------------- GEMM: C[M,N] = A[M,K] * Bt[N,K]^T  (bf16, m97-style) ----------------
// EPI 0: scatter-write bf16 Q/K/V as [B,H,T,D];  EPI 1: write f32 Od[M,N]

template <int EPI>
__global__ __launch_bounds__(256) void gemm_bt(
    const u16* __restrict__ A, const u16* __restrict__ Bt, int K,
    u16* __restrict__ Qd, u16* __restrict__ Kd, u16* __restrict__ Vd,
    float* __restrict__ Od, int N) {
  __shared__ u16 As[128 * 32];
  __shared__ u16 Bs[128 * 32];
  int tid = threadIdx.x;
  int l = tid & 63, w = tid >> 6;
  int wr = w >> 1, wc = w & 1;
  int lr = l & 15, lg = l >> 4;
  int m0 = blockIdx.y * 128, n0 = blockIdx.x * 128;

  f32x4 acc[4][4];
  f32x4 z4 = {0.f, 0.f, 0.f, 0.f};
#pragma unroll
  for (int mi = 0; mi < 4; ++mi)
#pragma unroll
    for (int ni = 0; ni < 4; ++ni) acc[mi][ni] = z4;

  for (int kt = 0; kt < K; kt += 32) {
#pragma unroll
    for (int it = 0; it < 2; ++it) {
      int q = it * 256 + tid;
      int r = q >> 2, s = q & 3;
      int sw = (s ^ (r & 3)) << 3;
      GLD16(A + (size_t)(m0 + r) * K + kt + sw, As + it * 2048 + w * 512);
      GLD16(Bt + (size_t)(n0 + r) * K + kt + sw, Bs + it * 2048 + w * 512);
    }
    __syncthreads();

    bf16x8 af[4], bfv[4];
#pragma unroll
    for (int mi = 0; mi < 4; ++mi) {
      int row = wr * 64 + mi * 16 + lr;
      af[mi] = *(const bf16x8*)&As[row * 32 + ((lg ^ (row & 3)) << 3)];
    }
#pragma unroll
    for (int ni = 0; ni < 4; ++ni) {
      int col = wc * 64 + ni * 16 + lr;
      bfv[ni] = *(const bf16x8*)&Bs[col * 32 + ((lg ^ (col & 3)) << 3)];
    }
#pragma unroll
    for (int mi = 0; mi < 4; ++mi)
#pragma unroll
      for (int ni = 0; ni < 4; ++ni)
        acc[mi][ni] = __builtin_amdgcn_mfma_f32_16x16x32_bf16(
            af[mi], bfv[ni], acc[mi][ni], 0, 0, 0);
    __syncthreads();
  }

  if (EPI == 0) {
    int s_blk = n0 >> 10;  // 0=Q 1=K 2=V (tile never straddles)
    u16* dst = (s_blk == 0) ? Qd : ((s_blk == 1) ? Kd : Vd);
#pragma unroll
    for (int mi = 0; mi < 4; ++mi)
#pragma unroll
      for (int ni = 0; ni < 4; ++ni)
#pragma unroll
        for (int i = 0; i < 4; ++i) {
          int m = m0 + wr * 64 + mi * 16 + lg * 4 + i;
          int n = n0 + wc * 64 + ni * 16 + lr;
          int b = m >> 11, t = m & 2047;
          int c = n & 1023, h = c >> 6, d = c & 63;
          dst[((size_t)(b * 16 + h) * 2048 + t) * 64 + d] = f2bf(acc[mi][ni][i]);
        }
  } else {
#pragma unroll
    for (int mi = 0; mi < 4; ++mi)
#pragma unroll
      for (int ni = 0; ni < 4; ++ni)
#pragma unroll
        for (int i = 0; i < 4; ++i) {
          int m = m0 + wr * 64 + mi * 16 + lg * 4 + i;
          int n = n0 + wc * 64 + ni * 16 + lr;
          Od[(size_t)m * N + n] = acc[mi][ni][i];
        }
  }
}

// ---------------- flash attention (causal) ----------------
// Q,K,V: bf16 [64][2048][64] ; Y: bf16 [8192][1024] at (b*2048+q)*1024 + h*64 + d

__global__ __launch_bounds__(256) void attn_fwd(
    const u16* __restrict__ Qg, const u16* __restrict__ Kg,
    const u16* __restrict__ Vg, u16* __restrict__ Yg) {
  __shared__ u16 Qs[128 * 64];
  __shared__ u16 Ks[64 * 64];
  __shared__ u16 Vt[64 * 72];      // V^T [d][t], stride 72 (16B-aligned rows)
  __shared__ u16 Ps[4][32 * 72];   // per-wave P, stride 72

  int tid = threadIdx.x;
  int l = tid & 63, w = tid >> 6;
  int lr = l & 15, lg = l >> 4;
  int qt = (int)gridDim.x - 1 - (int)blockIdx.x;  // heavy tiles first
  int bh = blockIdx.y;
  int qbase = qt * 128;
  const u16* Qb = Qg + (size_t)bh * 2048 * 64;
  const u16* Kb = Kg + (size_t)bh * 2048 * 64;
  const u16* Vb = Vg + (size_t)bh * 2048 * 64;

#pragma unroll
  for (int it = 0; it < 4; ++it) {  // Q tile, swizzled
    int q = it * 256 + tid;
    int r = q >> 3, s = q & 7;
    GLD16(Qb + (size_t)(qbase + r) * 64 + ((s ^ (r & 7)) << 3),
          Qs + it * 2048 + w * 512);
  }

  float m_run[2][4], l_run[2][4];
  f32x4 o_acc[2][4];
  f32x4 z4 = {0.f, 0.f, 0.f, 0.f};
#pragma unroll
  for (int mi = 0; mi < 2; ++mi)
#pragma unroll
    for (int i = 0; i < 4; ++i) {
      m_run[mi][i] = -1e30f;
      l_run[mi][i] = 0.f;
    }
#pragma unroll
  for (int mi = 0; mi < 2; ++mi)
#pragma unroll
    for (int nd = 0; nd < 4; ++nd) o_acc[mi][nd] = z4;

  int qw = qbase + w * 32;
  int jn = (qbase + 127) >> 6;
  for (int j = 0; j <= jn; ++j) {
    int kv0 = j * 64;
#pragma unroll
    for (int it = 0; it < 2; ++it) {  // K tile, swizzled
      int q = it * 256 + tid;
      int r = q >> 3, s = q & 7;
      GLD16(Kb + (size_t)(kv0 + r) * 64 + ((s ^ (r & 7)) << 3),
            Ks + it * 2048 + w * 512);
    }
#pragma unroll
    for (int it = 0; it < 2; ++it) {  // V tile, transposed into LDS
      int q = it * 256 + tid;
      int tr = q >> 3, d0 = (q & 7) << 3;
      u16x8 v = *(const u16x8*)(Vb + (size_t)(kv0 + tr) * 64 + d0);
#pragma unroll
      for (int jj = 0; jj < 8; ++jj) Vt[(d0 + jj) * 72 + tr] = v[jj];
    }
    __syncthreads();

    bool active = (kv0 <= qw + 31);
    if (active) {
      f32x4 s_acc[2][4];
#pragma unroll
      for (int mi = 0; mi < 2; ++mi)
#pragma unroll
        for (int ni = 0; ni < 4; ++ni) s_acc[mi][ni] = z4;
#pragma unroll
      for (int ks = 0; ks < 2; ++ks) {
        bf16x8 aq[2], bk[4];
        int sc = ks * 4 + lg;
#pragma unroll
        for (int mi = 0; mi < 2; ++mi) {
          int row = w * 32 + mi * 16 + lr;
          aq[mi] = *(const bf16x8*)&Qs[row * 64 + ((sc ^ (row & 7)) << 3)];
        }
#pragma unroll
        for (int ni = 0; ni < 4; ++ni) {
          int row = ni * 16 + lr;
          bk[ni] = *(const bf16x8*)&Ks[row * 64 + ((sc ^ (row & 7)) << 3)];
        }
#pragma unroll
        for (int mi = 0; mi < 2; ++mi)
#pragma unroll
          for (int ni = 0; ni < 4; ++ni)
            s_acc[mi][ni] = __builtin_amdgcn_mfma_f32_16x16x32_bf16(
                aq[mi], bk[ni], s_acc[mi][ni], 0, 0, 0);
      }
      u16* Pw = Ps[w];
#pragma unroll
      for (int mi = 0; mi < 2; ++mi)
#pragma unroll
        for (int i = 0; i < 4; ++i) {
          int qg = qbase + w * 32 + mi * 16 + lg * 4 + i;
          float sv[4];
#pragma unroll
          for (int ni = 0; ni < 4; ++ni) {
            int kg = kv0 + ni * 16 + lr;
            float xv = s_acc[mi][ni][i] * 0.125f;
            sv[ni] = (kg <= qg) ? xv : -1e30f;
          }
          float mx = fmaxf(fmaxf(sv[0], sv[1]), fmaxf(sv[2], sv[3]));
#pragma unroll
          for (int off = 1; off < 16; off <<= 1)
            mx = fmaxf(mx, __shfl_xor(mx, off));
          float mo = m_run[mi][i];
          float mn = fmaxf(mo, mx);
          float fsc = __expf(mo - mn);
          float ls = 0.f;
#pragma unroll
          for (int ni = 0; ni < 4; ++ni) {
            float p = __expf(sv[ni] - mn);
            ls += p;
            Pw[(mi * 16 + lg * 4 + i) * 72 + ni * 16 + lr] = f2bf(p);
          }
#pragma unroll
          for (int off = 1; off < 16; off <<= 1) ls += __shfl_xor(ls, off);
          l_run[mi][i] = l_run[mi][i] * fsc + ls;
          m_run[mi][i] = mn;
#pragma unroll
          for (int nd = 0; nd < 4; ++nd) o_acc[mi][nd][i] *= fsc;
        }
    }
    __syncthreads();  // Ps visible (and in-wave ds ordering)
    if (active) {
#pragma unroll
      for (int ks = 0; ks < 2; ++ks) {
        bf16x8 ap[2], bv[4];
#pragma unroll
        for (int mi = 0; mi < 2; ++mi)
          ap[mi] = *(const bf16x8*)&Ps[w][(mi * 16 + lr) * 72 + ks * 32 + lg * 8];
#pragma unroll
        for (int ni = 0; ni < 4; ++ni)
          bv[ni] = *(const bf16x8*)&Vt[(ni * 16 + lr) * 72 + ks * 32 + lg * 8];
#pragma unroll
        for (int mi = 0; mi < 2; ++mi)
#pragma unroll
          for (int ni = 0; ni < 4; ++ni)
            o_acc[mi][ni] = __builtin_amdgcn_mfma_f32_16x16x32_bf16(
                ap[mi], bv[ni], o_acc[mi][ni], 0, 0, 0);
      }
    }
    __syncthreads();  // protect Ks/Vt before next stage
  }

  int b = bh >> 4, h = bh & 15;
#pragma unroll
  for (int mi = 0; mi < 2; ++mi)
#pragma unroll
    for (int nd = 0; nd < 4; ++nd)
#pragma unroll
      for (int i = 0; i < 4; ++i) {
        int qg = qbase + w * 32 + mi * 16 + lg * 4 + i;
        int d = nd * 16 + lr;
        float y = o_acc[mi][nd][i] / l_run[mi][i];
        Yg[(size_t)(b * 2048 + qg) * 1024 + h * 64 + d] = f2bf(y);
      }
}

// ---------------- launch ----------------

extern "C" void kernel_launch(void* const* d_in, const int* in_sizes, int n_in,
                              void* d_out, int out_size, void* d_ws, size_t ws_size,
                              hipStream_t stream) {
  const float* x = (const float*)d_in[0];
  const float* w_qkv = (const float*)d_in[1];
  const float* w_proj = (const float*)d_in[2];
  float* out = (float*)d_out;
  u16* ws = (u16*)d_ws;

  u16* xb = ws;                  // 8388608 elems (B*T*C)
  u16* wq = xb + 8388608;        // 3145728 (3C x C, transposed)
  u16* wp = wq + 3145728;        // 1048576 (C x C, transposed)
  u16* Qb = wp + 1048576;        // 8388608 each, [B,H,T,D]
  u16* Kb = Qb + 8388608;
  u16* Vb = Kb + 8388608;
  u16* Yb = xb;                  // alias: x_bf16 dead after QKV GEMM

  cast_f32_bf16<<<8192, 256, 0, stream>>>(x, xb, 2097152);
  transpose_cast<<<dim3(96, 32), dim3(32, 8), 0, stream>>>(w_qkv, wq, 1024, 3072);
  transpose_cast<<<dim3(32, 32), dim3(32, 8), 0, stream>>>(w_proj, wp, 1024, 1024);
  gemm_bt<0><<<dim3(24, 64), 256, 0, stream>>>(xb, wq, 1024, Qb, Kb, Vb, nullptr, 3072);
  attn_fwd<<<dim3(16, 64), 256, 0, stream>>>(Qb, Kb, Vb, Yb);
  gemm_bt<1><<<dim3(8, 64), 256, 0, stream>>>(Yb, wp, 1024, nullptr, nullptr, nullptr, out, 1024);
}

// Round 3
// 242.731 us; speedup vs baseline: 1.6641x; 1.6641x over previous
//
#include <hip/hip_runtime.h>
#include <hip/hip_bf16.h>

typedef unsigned short u16;
typedef __bf16 bf16x8 __attribute__((ext_vector_type(8)));
typedef float f32x4 __attribute__((ext_vector_type(4)));
typedef float f32x16 __attribute__((ext_vector_type(16)));
typedef unsigned short u16x8 __attribute__((ext_vector_type(8)));
typedef unsigned short u16x4 __attribute__((ext_vector_type(4)));
typedef unsigned int u32x4 __attribute__((ext_vector_type(4)));

__device__ __forceinline__ u16 f2bf(float f) {
  unsigned u = __builtin_bit_cast(unsigned, f);
  u += 0x7FFFu + ((u >> 16) & 1u);
  return (u16)(u >> 16);
}

// async global->LDS, 16B per lane; lds base must be wave-uniform
#define GLD16(gp, lp)                                                          \
  __builtin_amdgcn_global_load_lds(                                            \
      (const __attribute__((address_space(1))) void*)(gp),                     \
      (__attribute__((address_space(3))) void*)(lp), 16, 0, 0)

// ---------------- cast kernels ----------------

__global__ __launch_bounds__(256) void cast_f32_bf16(
    const float* __restrict__ in, u16* __restrict__ out, int n4) {
  int i = blockIdx.x * 256 + threadIdx.x;
  if (i >= n4) return;
  float4 v = ((const float4*)in)[i];
  u16x4 o = {f2bf(v.x), f2bf(v.y), f2bf(v.z), f2bf(v.w)};
  *(u16x4*)(out + (size_t)i * 4) = o;
}

// out[c][r] = (bf16) in[r][c];  in: R x C f32, out: C x R bf16
__global__ __launch_bounds__(256) void transpose_cast(
    const float* __restrict__ in, u16* __restrict__ out, int R, int C) {
  __shared__ float t[32][33];
  int c0 = blockIdx.x * 32, r0 = blockIdx.y * 32;
  int tx = threadIdx.x, ty = threadIdx.y;
#pragma unroll
  for (int k = 0; k < 4; ++k)
    t[ty + 8 * k][tx] = in[(size_t)(r0 + ty + 8 * k) * C + c0 + tx];
  __syncthreads();
#pragma unroll
  for (int k = 0; k < 4; ++k)
    out[(size_t)(c0 + ty + 8 * k) * R + r0 + tx] = f2bf(t[tx][ty + 8 * k]);
}

// ---------------- GEMM: C[M,N] = A[M,K] * Bt[N,K]^T  (bf16, m97-style) ----------------

template <int EPI>
__global__ __launch_bounds__(256) void gemm_bt(
    const u16* __restrict__ A, const u16* __restrict__ Bt, int K,
    u16* __restrict__ Qd, u16* __restrict__ Kd, u16* __restrict__ Vd,
    float* __restrict__ Od, int N) {
  __shared__ u16 As[128 * 32];
  __shared__ u16 Bs[128 * 32];
  int tid = threadIdx.x;
  int l = tid & 63, w = tid >> 6;
  int wr = w >> 1, wc = w & 1;
  int lr = l & 15, lg = l >> 4;
  int m0 = blockIdx.y * 128, n0 = blockIdx.x * 128;

  f32x4 acc[4][4];
  f32x4 z4 = {0.f, 0.f, 0.f, 0.f};
#pragma unroll
  for (int mi = 0; mi < 4; ++mi)
#pragma unroll
    for (int ni = 0; ni < 4; ++ni) acc[mi][ni] = z4;

  for (int kt = 0; kt < K; kt += 32) {
#pragma unroll
    for (int it = 0; it < 2; ++it) {
      int q = it * 256 + tid;
      int r = q >> 2, s = q & 3;
      int sw = (s ^ (r & 3)) << 3;
      GLD16(A + (size_t)(m0 + r) * K + kt + sw, As + it * 2048 + w * 512);
      GLD16(Bt + (size_t)(n0 + r) * K + kt + sw, Bs + it * 2048 + w * 512);
    }
    __syncthreads();

    bf16x8 af[4], bfv[4];
#pragma unroll
    for (int mi = 0; mi < 4; ++mi) {
      int row = wr * 64 + mi * 16 + lr;
      af[mi] = *(const bf16x8*)&As[row * 32 + ((lg ^ (row & 3)) << 3)];
    }
#pragma unroll
    for (int ni = 0; ni < 4; ++ni) {
      int col = wc * 64 + ni * 16 + lr;
      bfv[ni] = *(const bf16x8*)&Bs[col * 32 + ((lg ^ (col & 3)) << 3)];
    }
#pragma unroll
    for (int mi = 0; mi < 4; ++mi)
#pragma unroll
      for (int ni = 0; ni < 4; ++ni)
        acc[mi][ni] = __builtin_amdgcn_mfma_f32_16x16x32_bf16(
            af[mi], bfv[ni], acc[mi][ni], 0, 0, 0);
    __syncthreads();
  }

  if (EPI == 0) {
    int s_blk = n0 >> 10;  // 0=Q 1=K 2=V (tile never straddles)
    u16* dst = (s_blk == 0) ? Qd : ((s_blk == 1) ? Kd : Vd);
#pragma unroll
    for (int mi = 0; mi < 4; ++mi)
#pragma unroll
      for (int ni = 0; ni < 4; ++ni)
#pragma unroll
        for (int i = 0; i < 4; ++i) {
          int m = m0 + wr * 64 + mi * 16 + lg * 4 + i;
          int n = n0 + wc * 64 + ni * 16 + lr;
          int b = m >> 11, t = m & 2047;
          int c = n & 1023, h = c >> 6, d = c & 63;
          dst[((size_t)(b * 16 + h) * 2048 + t) * 64 + d] = f2bf(acc[mi][ni][i]);
        }
  } else {
#pragma unroll
    for (int mi = 0; mi < 4; ++mi)
#pragma unroll
      for (int ni = 0; ni < 4; ++ni)
#pragma unroll
        for (int i = 0; i < 4; ++i) {
          int m = m0 + wr * 64 + mi * 16 + lg * 4 + i;
          int n = n0 + wc * 64 + ni * 16 + lr;
          Od[(size_t)m * N + n] = acc[mi][ni][i];
        }
  }
}

// ---------------- flash attention (causal), swapped-QK^T, 32x32x16 MFMA ----------------
// Q,K,V: bf16 [64 bh][2048][64] ; Y: bf16 [8192][1024] at (b*2048+q)*1024 + h*64 + d
// Block: 4 waves x 64 q-rows = 256 q. Per wave: q in regs, S^T via mfma(K,Q),
// softmax in-register (k lane-local), P->A-frag via 2 shfl_xor(32)/kstep, PV from V^T LDS.

__global__ __launch_bounds__(256, 2) void attn_fwd(
    const u16* __restrict__ Qg, const u16* __restrict__ Kg,
    const u16* __restrict__ Vg, u16* __restrict__ Yg) {
  __shared__ u16 Ks[2][64 * 64];  // [k][d], chunk-swizzled: lds chunk c holds global chunk c^(k&7)
  __shared__ u16 Vt[64 * 64];     // V^T [d][t], chunk(t) swizzled by (d&7)^((d>>3)&7)

  int tid = threadIdx.x;
  int l = tid & 63, w = tid >> 6;
  int l31 = l & 31, hi = l >> 5, l7 = l & 7;
  int bid = blockIdx.x;
  int qt = (0x21305647u >> ((bid >> 6) * 4)) & 0xF;  // balanced heavy-first order
  int bh = bid & 63;
  int q0w = qt * 256 + w * 64;
  const u16* Qb = Qg + (size_t)bh * 131072;
  const u16* Kb = Kg + (size_t)bh * 131072;
  const u16* Vb = Vg + (size_t)bh * 131072;

  // Q fragments in registers (B-operand: col=q=l31, rows d=16*ds+8*hi+j)
  bf16x8 qreg[2][4];
#pragma unroll
  for (int mi = 0; mi < 2; ++mi)
#pragma unroll
    for (int ds = 0; ds < 4; ++ds)
      qreg[mi][ds] = *(const bf16x8*)(Qb + (size_t)(q0w + mi * 32 + l31) * 64 +
                                      ds * 16 + hi * 8);

  f32x16 o_acc[2][2];
#pragma unroll
  for (int mi = 0; mi < 2; ++mi)
#pragma unroll
    for (int dt = 0; dt < 2; ++dt)
#pragma unroll
      for (int r = 0; r < 16; ++r) o_acc[mi][dt][r] = 0.f;
  float m_run[2] = {-3e38f, -3e38f};
  float l_run[2] = {0.f, 0.f};

  int jn = (qt * 256 + 255) >> 6;

  // prologue: stage K(0) async, V(0) into regs
  u16x8 vpre[2];
#pragma unroll
  for (int it = 0; it < 2; ++it) {
    int r = (it * 256 + tid) >> 3;
    GLD16(Kb + (size_t)r * 64 + (((tid & 7) ^ (r & 7)) << 3),
          &Ks[0][it * 2048 + w * 512]);
  }
#pragma unroll
  for (int it = 0; it < 2; ++it) {
    int q = it * 256 + tid;
    vpre[it] = *(const u16x8*)(Vb + (size_t)(q >> 3) * 64 + (q & 7) * 8);
  }

  for (int j = 0; j <= jn; ++j) {
    int kv0 = j * 64;
    const u16* ksb = Ks[j & 1];
    // write V^T tile j (swizzled, conflict-free)
#pragma unroll
    for (int it = 0; it < 2; ++it) {
      int q = it * 256 + tid;
      int tr = q >> 3, dq = q & 7;
#pragma unroll
      for (int jj = 0; jj < 8; ++jj) {
        int d = dq * 8 + jj;
        Vt[d * 64 + (((tr >> 3) ^ jj ^ dq) << 3) + (tr & 7)] = vpre[it][jj];
      }
    }
    __syncthreads();  // [A] K(j) landed (vmcnt drain), Vt visible

    if (j < jn) {  // prefetch next tile: hides HBM latency under compute
      int kv1 = kv0 + 64;
#pragma unroll
      for (int it = 0; it < 2; ++it) {
        int r = (it * 256 + tid) >> 3;
        GLD16(Kb + (size_t)(kv1 + r) * 64 + (((tid & 7) ^ (r & 7)) << 3),
              &Ks[(j + 1) & 1][it * 2048 + w * 512]);
      }
#pragma unroll
      for (int it = 0; it < 2; ++it) {
        int q = it * 256 + tid;
        vpre[it] = *(const u16x8*)(Vb + (size_t)(kv1 + (q >> 3)) * 64 + (q & 7) * 8);
      }
    }

    bool active = kv0 <= q0w + 63;
    if (active) {
      bf16x8 kf[2][4], vf[2][4];
#pragma unroll
      for (int kt = 0; kt < 2; ++kt)
#pragma unroll
        for (int ds = 0; ds < 4; ++ds)
          kf[kt][ds] = *(const bf16x8*)&ksb[(32 * kt + l31) * 64 +
                                            (((2 * ds + hi) ^ l7) << 3)];
#pragma unroll
      for (int dt = 0; dt < 2; ++dt)
#pragma unroll
        for (int ks = 0; ks < 4; ++ks) {
          int d = 32 * dt + l31;
          int ch = ((2 * ks + hi) ^ (d & 7) ^ ((d >> 3) & 7)) & 7;
          vf[dt][ks] = *(const bf16x8*)&Vt[d * 64 + (ch << 3)];
        }
      bool needmask = (kv0 + 63) > q0w;

#pragma unroll
      for (int mi = 0; mi < 2; ++mi) {
        int qg = q0w + mi * 32 + l31;
        // QK^T swapped: S^T[k][q]; lane col=q=l31, rows k=crow(r,hi)
        f32x16 sa[2];
#pragma unroll
        for (int kt = 0; kt < 2; ++kt) {
          f32x16 acc;
#pragma unroll
          for (int r = 0; r < 16; ++r) acc[r] = 0.f;
#pragma unroll
          for (int ds = 0; ds < 4; ++ds)
            acc = __builtin_amdgcn_mfma_f32_32x32x16_bf16(
                kf[kt][ds], qreg[mi][ds], acc, 0, 0, 0);
          sa[kt] = acc;
        }
        float mloc = -3e38f;
        if (needmask) {
#pragma unroll
          for (int kt = 0; kt < 2; ++kt)
#pragma unroll
            for (int r = 0; r < 16; ++r) {
              int kg = kv0 + kt * 32 + ((r & 3) + 8 * (r >> 2) + 4 * hi);
              float v = sa[kt][r];
              v = (kg <= qg) ? v : -8e30f;
              sa[kt][r] = v;
              mloc = fmaxf(mloc, v);
            }
        } else {
#pragma unroll
          for (int kt = 0; kt < 2; ++kt)
#pragma unroll
            for (int r = 0; r < 16; ++r) mloc = fmaxf(mloc, sa[kt][r]);
        }
        float mx = fmaxf(mloc, __shfl_xor(mloc, 32)) * 0.125f;
        if (!__all(mx <= m_run[mi] + 8.f)) {  // defer-max (T13)
          float mn = fmaxf(m_run[mi], mx);
          float fsc = __expf(m_run[mi] - mn);
          m_run[mi] = mn;
          l_run[mi] *= fsc;
#pragma unroll
          for (int r = 0; r < 16; ++r) {
            float fv = __shfl(fsc, (r & 3) + 8 * (r >> 2) + 4 * hi + 32 * hi);
            o_acc[mi][0][r] *= fv;
            o_acc[mi][1][r] *= fv;
          }
        }
        float m8 = m_run[mi];
        float lloc = 0.f;
#pragma unroll
        for (int kt = 0; kt < 2; ++kt)
#pragma unroll
          for (int r = 0; r < 16; ++r) {
            float p = __expf(sa[kt][r] * 0.125f - m8);
            sa[kt][r] = p;
            lloc += p;
          }
        l_run[mi] += lloc + __shfl_xor(lloc, 32);
        // pack P to bf16 pairs (regs 2m,2m+1 -> one dword)
        unsigned pk0[8], pk1[8];
#pragma unroll
        for (int m = 0; m < 8; ++m) {
          pk0[m] = ((unsigned)f2bf(sa[0][2 * m + 1]) << 16) | f2bf(sa[0][2 * m]);
          pk1[m] = ((unsigned)f2bf(sa[1][2 * m + 1]) << 16) | f2bf(sa[1][2 * m]);
        }
        // build PV A-frags via one shfl_xor(32) pair per kstep
#pragma unroll
        for (int ks = 0; ks < 4; ++ks) {
          int c0 = 4 * (ks & 1);
          unsigned a0 = (ks < 2) ? pk0[c0] : pk1[c0];
          unsigned a1 = (ks < 2) ? pk0[c0 + 1] : pk1[c0 + 1];
          unsigned a2 = (ks < 2) ? pk0[c0 + 2] : pk1[c0 + 2];
          unsigned a3 = (ks < 2) ? pk0[c0 + 3] : pk1[c0 + 3];
          unsigned pubX = hi ? a0 : a2;
          unsigned pubY = hi ? a1 : a3;
          unsigned rx = (unsigned)__shfl_xor((int)pubX, 32);
          unsigned ry = (unsigned)__shfl_xor((int)pubY, 32);
          u32x4 fa;
          fa.x = hi ? rx : a0;
          fa.y = hi ? ry : a1;
          fa.z = hi ? a2 : rx;
          fa.w = hi ? a3 : ry;
          bf16x8 paf = __builtin_bit_cast(bf16x8, fa);
#pragma unroll
          for (int dt = 0; dt < 2; ++dt)
            o_acc[mi][dt] = __builtin_amdgcn_mfma_f32_32x32x16_bf16(
                paf, vf[dt][ks], o_acc[mi][dt], 0, 0, 0);
        }
      }
    }
    __syncthreads();  // [B] Ks(j)/Vt reads done; drains prefetches after compute
  }

  // epilogue: normalize and store
  int b = bh >> 4, h = bh & 15;
#pragma unroll
  for (int mi = 0; mi < 2; ++mi) {
#pragma unroll
    for (int r = 0; r < 16; ++r) {
      int crow = (r & 3) + 8 * (r >> 2) + 4 * hi;
      float li = __shfl(l_run[mi], crow + 32 * hi);
      float inv = 1.f / li;
      int q = q0w + mi * 32 + crow;
#pragma unroll
      for (int dt = 0; dt < 2; ++dt) {
        float y = o_acc[mi][dt][r] * inv;
        Yg[(size_t)(b * 2048 + q) * 1024 + h * 64 + dt * 32 + l31] = f2bf(y);
      }
    }
  }
}

// ---------------- launch ----------------

extern "C" void kernel_launch(void* const* d_in, const int* in_sizes, int n_in,
                              void* d_out, int out_size, void* d_ws, size_t ws_size,
                              hipStream_t stream) {
  const float* x = (const float*)d_in[0];
  const float* w_qkv = (const float*)d_in[1];
  const float* w_proj = (const float*)d_in[2];
  float* out = (float*)d_out;
  u16* ws = (u16*)d_ws;

  u16* xb = ws;                  // 8388608 elems (B*T*C)
  u16* wq = xb + 8388608;        // 3145728 (3C x C, transposed)
  u16* wp = wq + 3145728;        // 1048576 (C x C, transposed)
  u16* Qb = wp + 1048576;        // 8388608 each, [B,H,T,D]
  u16* Kb = Qb + 8388608;
  u16* Vb = Kb + 8388608;
  u16* Yb = xb;                  // alias: x_bf16 dead after QKV GEMM

  cast_f32_bf16<<<8192, 256, 0, stream>>>(x, xb, 2097152);
  transpose_cast<<<dim3(96, 32), dim3(32, 8), 0, stream>>>(w_qkv, wq, 1024, 3072);
  transpose_cast<<<dim3(32, 32), dim3(32, 8), 0, stream>>>(w_proj, wp, 1024, 1024);
  gemm_bt<0><<<dim3(24, 64), 256, 0, stream>>>(xb, wq, 1024, Qb, Kb, Vb, nullptr, 3072);
  attn_fwd<<<512, 256, 0, stream>>>(Qb, Kb, Vb, Yb);
  gemm_bt<1><<<dim3(8, 64), 256, 0, stream>>>(Yb, wp, 1024, nullptr, nullptr, nullptr, out, 1024);
}

// Round 4
// 238.292 us; speedup vs baseline: 1.6951x; 1.0186x over previous
//
#include <hip/hip_runtime.h>
#include <hip/hip_bf16.h>

typedef unsigned short u16;
typedef __bf16 bf16x8 __attribute__((ext_vector_type(8)));
typedef float f32x4 __attribute__((ext_vector_type(4)));
typedef float f32x16 __attribute__((ext_vector_type(16)));
typedef unsigned short u16x8 __attribute__((ext_vector_type(8)));
typedef unsigned short u16x4 __attribute__((ext_vector_type(4)));
typedef unsigned int u32x4 __attribute__((ext_vector_type(4)));

__device__ __forceinline__ u16 f2bf(float f) {
  unsigned u = __builtin_bit_cast(unsigned, f);
  u += 0x7FFFu + ((u >> 16) & 1u);
  return (u16)(u >> 16);
}

// packed f32x2 -> bf16x2 (RNE), single VALU instr
__device__ __forceinline__ unsigned cvt_pk_bf16(float lo, float hi_) {
  unsigned r;
  asm("v_cvt_pk_bf16_f32 %0, %1, %2" : "=v"(r) : "v"(lo), "v"(hi_));
  return r;
}

// async global->LDS, 16B per lane; lds base must be wave-uniform
#define GLD16(gp, lp)                                                          \
  __builtin_amdgcn_global_load_lds(                                            \
      (const __attribute__((address_space(1))) void*)(gp),                     \
      (__attribute__((address_space(3))) void*)(lp), 16, 0, 0)

// ---------------- cast kernels ----------------

__global__ __launch_bounds__(256) void cast_f32_bf16(
    const float* __restrict__ in, u16* __restrict__ out, int n4) {
  int i = blockIdx.x * 256 + threadIdx.x;
  if (i >= n4) return;
  float4 v = ((const float4*)in)[i];
  u16x4 o = {f2bf(v.x), f2bf(v.y), f2bf(v.z), f2bf(v.w)};
  *(u16x4*)(out + (size_t)i * 4) = o;
}

// out[c][r] = (bf16) in[r][c];  in: R x C f32, out: C x R bf16
__global__ __launch_bounds__(256) void transpose_cast(
    const float* __restrict__ in, u16* __restrict__ out, int R, int C) {
  __shared__ float t[32][33];
  int c0 = blockIdx.x * 32, r0 = blockIdx.y * 32;
  int tx = threadIdx.x, ty = threadIdx.y;
#pragma unroll
  for (int k = 0; k < 4; ++k)
    t[ty + 8 * k][tx] = in[(size_t)(r0 + ty + 8 * k) * C + c0 + tx];
  __syncthreads();
#pragma unroll
  for (int k = 0; k < 4; ++k)
    out[(size_t)(c0 + ty + 8 * k) * R + r0 + tx] = f2bf(t[tx][ty + 8 * k]);
}

// ---------------- GEMM: C[M,N] = A[M,K] * Bt[N,K]^T  (bf16, m97-style) ----------------

template <int EPI>
__global__ __launch_bounds__(256) void gemm_bt(
    const u16* __restrict__ A, const u16* __restrict__ Bt, int K,
    u16* __restrict__ Qd, u16* __restrict__ Kd, u16* __restrict__ Vd,
    float* __restrict__ Od, int N) {
  __shared__ u16 As[128 * 32];
  __shared__ u16 Bs[128 * 32];
  int tid = threadIdx.x;
  int l = tid & 63, w = tid >> 6;
  int wr = w >> 1, wc = w & 1;
  int lr = l & 15, lg = l >> 4;
  int m0 = blockIdx.y * 128, n0 = blockIdx.x * 128;

  f32x4 acc[4][4];
  f32x4 z4 = {0.f, 0.f, 0.f, 0.f};
#pragma unroll
  for (int mi = 0; mi < 4; ++mi)
#pragma unroll
    for (int ni = 0; ni < 4; ++ni) acc[mi][ni] = z4;

  for (int kt = 0; kt < K; kt += 32) {
#pragma unroll
    for (int it = 0; it < 2; ++it) {
      int q = it * 256 + tid;
      int r = q >> 2, s = q & 3;
      int sw = (s ^ (r & 3)) << 3;
      GLD16(A + (size_t)(m0 + r) * K + kt + sw, As + it * 2048 + w * 512);
      GLD16(Bt + (size_t)(n0 + r) * K + kt + sw, Bs + it * 2048 + w * 512);
    }
    __syncthreads();

    bf16x8 af[4], bfv[4];
#pragma unroll
    for (int mi = 0; mi < 4; ++mi) {
      int row = wr * 64 + mi * 16 + lr;
      af[mi] = *(const bf16x8*)&As[row * 32 + ((lg ^ (row & 3)) << 3)];
    }
#pragma unroll
    for (int ni = 0; ni < 4; ++ni) {
      int col = wc * 64 + ni * 16 + lr;
      bfv[ni] = *(const bf16x8*)&Bs[col * 32 + ((lg ^ (col & 3)) << 3)];
    }
#pragma unroll
    for (int mi = 0; mi < 4; ++mi)
#pragma unroll
      for (int ni = 0; ni < 4; ++ni)
        acc[mi][ni] = __builtin_amdgcn_mfma_f32_16x16x32_bf16(
            af[mi], bfv[ni], acc[mi][ni], 0, 0, 0);
    __syncthreads();
  }

  if (EPI == 0) {
    int s_blk = n0 >> 10;  // 0=Q 1=K 2=V (tile never straddles)
    u16* dst = (s_blk == 0) ? Qd : ((s_blk == 1) ? Kd : Vd);
#pragma unroll
    for (int mi = 0; mi < 4; ++mi)
#pragma unroll
      for (int ni = 0; ni < 4; ++ni)
#pragma unroll
        for (int i = 0; i < 4; ++i) {
          int m = m0 + wr * 64 + mi * 16 + lg * 4 + i;
          int n = n0 + wc * 64 + ni * 16 + lr;
          int b = m >> 11, t = m & 2047;
          int c = n & 1023, h = c >> 6, d = c & 63;
          dst[((size_t)(b * 16 + h) * 2048 + t) * 64 + d] = f2bf(acc[mi][ni][i]);
        }
  } else {
#pragma unroll
    for (int mi = 0; mi < 4; ++mi)
#pragma unroll
      for (int ni = 0; ni < 4; ++ni)
#pragma unroll
        for (int i = 0; i < 4; ++i) {
          int m = m0 + wr * 64 + mi * 16 + lg * 4 + i;
          int n = n0 + wc * 64 + ni * 16 + lr;
          Od[(size_t)m * N + n] = acc[mi][ni][i];
        }
  }
}

// ---------------- flash attention (causal), swapped-QK^T, 32x32x16 MFMA ----------------
// Q,K,V: bf16 [64 bh][2048][64] ; Y: bf16 [8192][1024] at (b*2048+q)*1024 + h*64 + d
// Block: 4 waves x 32 q-rows = 128 q. Grid: 16 qt x 64 bh = 1024 blocks (4/CU).
// Per wave: Q in regs, S^T via mfma(K,Q), in-register softmax (k lane-local),
// P pack via v_cvt_pk_bf16_f32, P->A-frag via 2 shfl_xor(32)/kstep, PV from V^T LDS.

__global__ __launch_bounds__(256, 4) void attn_fwd(
    const u16* __restrict__ Qg, const u16* __restrict__ Kg,
    const u16* __restrict__ Vg, u16* __restrict__ Yg) {
  __shared__ u16 Ks[2][64 * 64];  // [k][d], chunk c holds global chunk c^(k&7)
  __shared__ u16 Vt[64 * 64];     // V^T [d][t], t-chunk swizzled by (d&7)^(d>>3)

  int tid = threadIdx.x;
  int l = tid & 63, w = tid >> 6;
  int l31 = l & 31, hi = l >> 5, l7 = l & 7;
  int bid = blockIdx.x;
  // per-CU-quadruple balanced qt order: {g,g+4,g+8,g+12} sums equal, heavy first
  int qt = (int)((0x01237654ba98cdefULL >> ((bid >> 6) * 4)) & 0xF);
  int bh = bid & 63;
  int q0w = qt * 128 + w * 32;
  const u16* Qb = Qg + (size_t)bh * 131072;
  const u16* Kb = Kg + (size_t)bh * 131072;
  const u16* Vb = Vg + (size_t)bh * 131072;

  int vtr = tid >> 3, vdq = tid & 7;  // V staging coords (2 rows/thread)

  // Q fragments in registers (B-operand: col=q=l31, rows d=16*ds+8*hi+j)
  bf16x8 qreg[4];
#pragma unroll
  for (int ds = 0; ds < 4; ++ds)
    qreg[ds] = *(const bf16x8*)(Qb + (size_t)(q0w + l31) * 64 + ds * 16 + hi * 8);

  f32x16 o_acc[2];
#pragma unroll
  for (int dt = 0; dt < 2; ++dt)
#pragma unroll
    for (int r = 0; r < 16; ++r) o_acc[dt][r] = 0.f;
  float m_run = -3e38f, l_run = 0.f;

  int jn = 2 * qt + 1;

  // prologue: stage K(0) async, V(0) rows 2vtr,2vtr+1 into regs
  u16x8 va, vb;
#pragma unroll
  for (int it = 0; it < 2; ++it) {
    int r = (it * 256 + tid) >> 3;
    GLD16(Kb + (size_t)r * 64 + (((tid & 7) ^ (r & 7)) << 3),
          &Ks[0][it * 2048 + w * 512]);
  }
  va = *(const u16x8*)(Vb + (size_t)(2 * vtr) * 64 + vdq * 8);
  vb = *(const u16x8*)(Vb + (size_t)(2 * vtr + 1) * 64 + vdq * 8);

  for (int j = 0; j <= jn; ++j) {
    int kv0 = j * 64;
    const u16* ksb = Ks[j & 1];
    // write V^T tile j: paired u32 (t=2vtr,2vtr+1), swizzled, conflict-free
#pragma unroll
    for (int jj = 0; jj < 8; ++jj) {
      int d = vdq * 8 + jj;
      unsigned wv = (unsigned)va[jj] | ((unsigned)vb[jj] << 16);
      *(unsigned*)(Vt + d * 64 + (((vtr >> 2) ^ jj ^ vdq) << 3) +
                   ((vtr & 3) << 1)) = wv;
    }
    __syncthreads();  // [A] K(j) landed (vmcnt drain), Vt visible

    if (j < jn) {  // prefetch next tile: hides HBM latency under compute
      int kv1 = kv0 + 64;
#pragma unroll
      for (int it = 0; it < 2; ++it) {
        int r = (it * 256 + tid) >> 3;
        GLD16(Kb + (size_t)(kv1 + r) * 64 + (((tid & 7) ^ (r & 7)) << 3),
              &Ks[(j + 1) & 1][it * 2048 + w * 512]);
      }
      va = *(const u16x8*)(Vb + (size_t)(kv1 + 2 * vtr) * 64 + vdq * 8);
      vb = *(const u16x8*)(Vb + (size_t)(kv1 + 2 * vtr + 1) * 64 + vdq * 8);
    }

    bool active = kv0 <= q0w + 31;
    if (active) {
      int qg = q0w + l31;
      bf16x8 kf[2][4];
#pragma unroll
      for (int kt = 0; kt < 2; ++kt)
#pragma unroll
        for (int ds = 0; ds < 4; ++ds)
          kf[kt][ds] = *(const bf16x8*)&ksb[(32 * kt + l31) * 64 +
                                            (((2 * ds + hi) ^ l7) << 3)];
      // QK^T swapped: S^T[k][q]; lane col=q=l31, rows k=crow(r,hi)
      f32x16 sa[2];
      __builtin_amdgcn_s_setprio(1);
#pragma unroll
      for (int kt = 0; kt < 2; ++kt) {
        f32x16 acc;
#pragma unroll
        for (int r = 0; r < 16; ++r) acc[r] = 0.f;
#pragma unroll
        for (int ds = 0; ds < 4; ++ds)
          acc = __builtin_amdgcn_mfma_f32_32x32x16_bf16(kf[kt][ds], qreg[ds],
                                                        acc, 0, 0, 0);
        sa[kt] = acc;
      }
      __builtin_amdgcn_s_setprio(0);

      float mloc = -3e38f;
      if (kv0 + 63 > q0w) {  // masking tile
#pragma unroll
        for (int kt = 0; kt < 2; ++kt)
#pragma unroll
          for (int r = 0; r < 16; ++r) {
            int kg = kv0 + kt * 32 + ((r & 3) + 8 * (r >> 2) + 4 * hi);
            float v = sa[kt][r];
            v = (kg <= qg) ? v : -8e30f;
            sa[kt][r] = v;
            mloc = fmaxf(mloc, v);
          }
      } else {
#pragma unroll
        for (int kt = 0; kt < 2; ++kt)
#pragma unroll
          for (int r = 0; r < 16; ++r) mloc = fmaxf(mloc, sa[kt][r]);
      }
      float mx = fmaxf(mloc, __shfl_xor(mloc, 32)) * 0.125f;
      if (!__all(mx <= m_run + 8.f)) {  // defer-max (T13)
        float mn = fmaxf(m_run, mx);
        float fsc = __expf(m_run - mn);
        m_run = mn;
        l_run *= fsc;
#pragma unroll
        for (int r = 0; r < 16; ++r) {
          float fv = __shfl(fsc, (r & 3) + 8 * (r >> 2) + 4 * hi + 32 * hi);
          o_acc[0][r] *= fv;
          o_acc[1][r] *= fv;
        }
      }
      // p = exp2(s*0.125*log2e - m*log2e): 1 fma + 1 exp2 per element
      float mm = m_run * 1.44269504f;
      float lloc = 0.f;
#pragma unroll
      for (int kt = 0; kt < 2; ++kt)
#pragma unroll
        for (int r = 0; r < 16; ++r) {
          float p = exp2f(__builtin_fmaf(sa[kt][r], 0.18033688f, -mm));
          sa[kt][r] = p;
          lloc += p;
        }
      l_run += lloc + __shfl_xor(lloc, 32);
      // pack P to bf16 pairs (1 cvt_pk each)
      unsigned pk0[8], pk1[8];
#pragma unroll
      for (int m = 0; m < 8; ++m) {
        pk0[m] = cvt_pk_bf16(sa[0][2 * m], sa[0][2 * m + 1]);
        pk1[m] = cvt_pk_bf16(sa[1][2 * m], sa[1][2 * m + 1]);
      }
      // V^T fragments (loaded late to bound live VGPRs)
      bf16x8 vf[2][4];
#pragma unroll
      for (int dt = 0; dt < 2; ++dt)
#pragma unroll
        for (int ks = 0; ks < 4; ++ks) {
          int d = 32 * dt + l31;
          int ch = ((2 * ks + hi) ^ (d & 7) ^ ((d >> 3) & 7)) & 7;
          vf[dt][ks] = *(const bf16x8*)&Vt[d * 64 + (ch << 3)];
        }
      // build PV A-frags via one shfl_xor(32) pair per kstep
#pragma unroll
      for (int ks = 0; ks < 4; ++ks) {
        int c0 = 4 * (ks & 1);
        unsigned a0 = (ks < 2) ? pk0[c0] : pk1[c0];
        unsigned a1 = (ks < 2) ? pk0[c0 + 1] : pk1[c0 + 1];
        unsigned a2 = (ks < 2) ? pk0[c0 + 2] : pk1[c0 + 2];
        unsigned a3 = (ks < 2) ? pk0[c0 + 3] : pk1[c0 + 3];
        unsigned pubX = hi ? a0 : a2;
        unsigned pubY = hi ? a1 : a3;
        unsigned rx = (unsigned)__shfl_xor((int)pubX, 32);
        unsigned ry = (unsigned)__shfl_xor((int)pubY, 32);
        u32x4 fa;
        fa.x = hi ? rx : a0;
        fa.y = hi ? ry : a1;
        fa.z = hi ? a2 : rx;
        fa.w = hi ? a3 : ry;
        bf16x8 paf = __builtin_bit_cast(bf16x8, fa);
        __builtin_amdgcn_s_setprio(1);
#pragma unroll
        for (int dt = 0; dt < 2; ++dt)
          o_acc[dt] = __builtin_amdgcn_mfma_f32_32x32x16_bf16(
              paf, vf[dt][ks], o_acc[dt], 0, 0, 0);
        __builtin_amdgcn_s_setprio(0);
      }
    }
    __syncthreads();  // [B] Ks(j)/Vt reads done before next tile's writes
  }

  // epilogue: normalize and store
  int b = bh >> 4, h = bh & 15;
#pragma unroll
  for (int r = 0; r < 16; ++r) {
    int crow = (r & 3) + 8 * (r >> 2) + 4 * hi;
    float li = __shfl(l_run, crow + 32 * hi);
    float inv = 1.f / li;
    int q = q0w + crow;
#pragma unroll
    for (int dt = 0; dt < 2; ++dt) {
      float y = o_acc[dt][r] * inv;
      Yg[(size_t)(b * 2048 + q) * 1024 + h * 64 + dt * 32 + l31] = f2bf(y);
    }
  }
}

// ---------------- launch ----------------

extern "C" void kernel_launch(void* const* d_in, const int* in_sizes, int n_in,
                              void* d_out, int out_size, void* d_ws, size_t ws_size,
                              hipStream_t stream) {
  const float* x = (const float*)d_in[0];
  const float* w_qkv = (const float*)d_in[1];
  const float* w_proj = (const float*)d_in[2];
  float* out = (float*)d_out;
  u16* ws = (u16*)d_ws;

  u16* xb = ws;                  // 8388608 elems (B*T*C)
  u16* wq = xb + 8388608;        // 3145728 (3C x C, transposed)
  u16* wp = wq + 3145728;        // 1048576 (C x C, transposed)
  u16* Qb = wp + 1048576;        // 8388608 each, [B,H,T,D]
  u16* Kb = Qb + 8388608;
  u16* Vb = Kb + 8388608;
  u16* Yb = xb;                  // alias: x_bf16 dead after QKV GEMM

  cast_f32_bf16<<<8192, 256, 0, stream>>>(x, xb, 2097152);
  transpose_cast<<<dim3(96, 32), dim3(32, 8), 0, stream>>>(w_qkv, wq, 1024, 3072);
  transpose_cast<<<dim3(32, 32), dim3(32, 8), 0, stream>>>(w_proj, wp, 1024, 1024);
  gemm_bt<0><<<dim3(24, 64), 256, 0, stream>>>(xb, wq, 1024, Qb, Kb, Vb, nullptr, 3072);
  attn_fwd<<<1024, 256, 0, stream>>>(Qb, Kb, Vb, Yb);
  gemm_bt<1><<<dim3(8, 64), 256, 0, stream>>>(Yb, wp, 1024, nullptr, nullptr, nullptr, out, 1024);
}

// Round 6
// 205.142 us; speedup vs baseline: 1.9690x; 1.1616x over previous
//
#include <hip/hip_runtime.h>
#include <hip/hip_bf16.h>

typedef unsigned short u16;
typedef __bf16 bf16x8 __attribute__((ext_vector_type(8)));
typedef float f32x4 __attribute__((ext_vector_type(4)));
typedef float f32x16 __attribute__((ext_vector_type(16)));
typedef unsigned short u16x8 __attribute__((ext_vector_type(8)));
typedef unsigned short u16x4 __attribute__((ext_vector_type(4)));
typedef unsigned int u32x4 __attribute__((ext_vector_type(4)));

__device__ __forceinline__ u16 f2bf(float f) {
  unsigned u = __builtin_bit_cast(unsigned, f);
  u += 0x7FFFu + ((u >> 16) & 1u);
  return (u16)(u >> 16);
}

// packed f32x2 -> bf16x2 (RNE), single VALU instr
__device__ __forceinline__ unsigned cvt_pk_bf16(float lo, float hi_) {
  unsigned r;
  asm("v_cvt_pk_bf16_f32 %0, %1, %2" : "=v"(r) : "v"(lo), "v"(hi_));
  return r;
}

// async global->LDS, 16B per lane; lds base must be wave-uniform
#define GLD16(gp, lp)                                                          \
  __builtin_amdgcn_global_load_lds(                                            \
      (const __attribute__((address_space(1))) void*)(gp),                     \
      (__attribute__((address_space(3))) void*)(lp), 16, 0, 0)

// ---------------- cast kernels ----------------

__global__ __launch_bounds__(256) void cast_f32_bf16(
    const float* __restrict__ in, u16* __restrict__ out, int n4) {
  int i = blockIdx.x * 256 + threadIdx.x;
  if (i >= n4) return;
  float4 v = ((const float4*)in)[i];
  u16x4 o = {f2bf(v.x), f2bf(v.y), f2bf(v.z), f2bf(v.w)};
  *(u16x4*)(out + (size_t)i * 4) = o;
}

// out[c][r] = (bf16) in[r][c];  in: R x C f32, out: C x R bf16
__global__ __launch_bounds__(256) void transpose_cast(
    const float* __restrict__ in, u16* __restrict__ out, int R, int C) {
  __shared__ float t[32][33];
  int c0 = blockIdx.x * 32, r0 = blockIdx.y * 32;
  int tx = threadIdx.x, ty = threadIdx.y;
#pragma unroll
  for (int k = 0; k < 4; ++k)
    t[ty + 8 * k][tx] = in[(size_t)(r0 + ty + 8 * k) * C + c0 + tx];
  __syncthreads();
#pragma unroll
  for (int k = 0; k < 4; ++k)
    out[(size_t)(c0 + ty + 8 * k) * R + r0 + tx] = f2bf(t[tx][ty + 8 * k]);
}

// ---------------- GEMM: C[M,N] = A[M,K] * Bt[N,K]^T  (bf16, m97-style) ----------------

template <int EPI>
__global__ __launch_bounds__(256) void gemm_bt(
    const u16* __restrict__ A, const u16* __restrict__ Bt, int K,
    u16* __restrict__ Qd, u16* __restrict__ Kd, u16* __restrict__ Vd,
    float* __restrict__ Od, int N) {
  __shared__ u16 As[128 * 32];
  __shared__ u16 Bs[128 * 32];
  int tid = threadIdx.x;
  int l = tid & 63, w = tid >> 6;
  int wr = w >> 1, wc = w & 1;
  int lr = l & 15, lg = l >> 4;
  int m0 = blockIdx.y * 128, n0 = blockIdx.x * 128;

  f32x4 acc[4][4];
  f32x4 z4 = {0.f, 0.f, 0.f, 0.f};
#pragma unroll
  for (int mi = 0; mi < 4; ++mi)
#pragma unroll
    for (int ni = 0; ni < 4; ++ni) acc[mi][ni] = z4;

  for (int kt = 0; kt < K; kt += 32) {
#pragma unroll
    for (int it = 0; it < 2; ++it) {
      int q = it * 256 + tid;
      int r = q >> 2, s = q & 3;
      int sw = (s ^ (r & 3)) << 3;
      GLD16(A + (size_t)(m0 + r) * K + kt + sw, As + it * 2048 + w * 512);
      GLD16(Bt + (size_t)(n0 + r) * K + kt + sw, Bs + it * 2048 + w * 512);
    }
    __syncthreads();

    bf16x8 af[4], bfv[4];
#pragma unroll
    for (int mi = 0; mi < 4; ++mi) {
      int row = wr * 64 + mi * 16 + lr;
      af[mi] = *(const bf16x8*)&As[row * 32 + ((lg ^ (row & 3)) << 3)];
    }
#pragma unroll
    for (int ni = 0; ni < 4; ++ni) {
      int col = wc * 64 + ni * 16 + lr;
      bfv[ni] = *(const bf16x8*)&Bs[col * 32 + ((lg ^ (col & 3)) << 3)];
    }
#pragma unroll
    for (int mi = 0; mi < 4; ++mi)
#pragma unroll
      for (int ni = 0; ni < 4; ++ni)
        acc[mi][ni] = __builtin_amdgcn_mfma_f32_16x16x32_bf16(
            af[mi], bfv[ni], acc[mi][ni], 0, 0, 0);
    __syncthreads();
  }

  if (EPI == 0) {
    int s_blk = n0 >> 10;  // 0=Q 1=K 2=V (tile never straddles)
    u16* dst = (s_blk == 0) ? Qd : ((s_blk == 1) ? Kd : Vd);
#pragma unroll
    for (int mi = 0; mi < 4; ++mi)
#pragma unroll
      for (int ni = 0; ni < 4; ++ni)
#pragma unroll
        for (int i = 0; i < 4; ++i) {
          int m = m0 + wr * 64 + mi * 16 + lg * 4 + i;
          int n = n0 + wc * 64 + ni * 16 + lr;
          int b = m >> 11, t = m & 2047;
          int c = n & 1023, h = c >> 6, d = c & 63;
          dst[((size_t)(b * 16 + h) * 2048 + t) * 64 + d] = f2bf(acc[mi][ni][i]);
        }
  } else {
#pragma unroll
    for (int mi = 0; mi < 4; ++mi)
#pragma unroll
      for (int ni = 0; ni < 4; ++ni)
#pragma unroll
        for (int i = 0; i < 4; ++i) {
          int m = m0 + wr * 64 + mi * 16 + lg * 4 + i;
          int n = n0 + wc * 64 + ni * 16 + lr;
          Od[(size_t)m * N + n] = acc[mi][ni][i];
        }
  }
}

// ---------------- flash attention (causal), swapped-QK^T, 32x32x16 MFMA ----------------
// Q,K,V: bf16 [64 bh][2048][64] ; Y: bf16 [8192][1024] at (b*2048+q)*1024 + h*64 + d
// Block: 8 waves x 32 q-rows = 256-row q-tile. Each block runs TWO complementary
// q-tiles {pp, 7-pp} -> exactly 36 k-tile iterations per block (perfect balance).
// Grid: 4 pairs x 64 bh = 256 blocks = 1/CU, 16 waves/CU.

__global__ __launch_bounds__(512, 2) void attn_fwd(
    const u16* __restrict__ Qg, const u16* __restrict__ Kg,
    const u16* __restrict__ Vg, u16* __restrict__ Yg) {
  __shared__ u16 Ks[2][64 * 64];  // [k][d], octet c holds global octet c^(k&7)
  __shared__ u16 Vt[64 * 64];     // V^T [d][t], t-octet swizzled by (t>>3)^(d&7)^(d>>3)

  int tid = threadIdx.x;
  int l = tid & 63, w = tid >> 6;        // 8 waves
  int l31 = l & 31, hi = l >> 5, l7 = l & 7;
  int bid = blockIdx.x;
  int pp = bid >> 6;                     // 0..3 (pair id)
  int bh = bid & 63;
  const u16* Qb = Qg + (size_t)bh * 131072;
  const u16* Kb = Kg + (size_t)bh * 131072;
  const u16* Vb = Vg + (size_t)bh * 131072;
  int b = bh >> 4, h = bh & 15;

  int vt_ = tid >> 3, vdq = tid & 7;     // V staging: one row-octet per thread
  int kr = tid >> 3, ks8 = tid & 7;      // K staging coords

#pragma unroll 1
  for (int ph = 0; ph < 2; ++ph) {
    int qt = ph ? (7 - pp) : pp;
    int q0w = qt * 256 + w * 32;
    int jn = 4 * qt + 3;  // odd -> phase boundary buffer parity safe

    // Q fragments in registers (B-operand: col=q=l31, rows d=16*ds+8*hi+j)
    bf16x8 qreg[4];
#pragma unroll
    for (int ds = 0; ds < 4; ++ds)
      qreg[ds] =
          *(const bf16x8*)(Qb + (size_t)(q0w + l31) * 64 + ds * 16 + hi * 8);

    f32x16 o_acc[2];
#pragma unroll
    for (int dt = 0; dt < 2; ++dt)
#pragma unroll
      for (int r = 0; r < 16; ++r) o_acc[dt][r] = 0.f;
    float m_run = -3e38f, l_run = 0.f;

    // prologue: stage K(0) async, V(0) row-octet into regs
    u16x8 va;
    GLD16(Kb + (size_t)kr * 64 + ((ks8 ^ (kr & 7)) << 3), &Ks[0][0] + w * 512);
    va = *(const u16x8*)(Vb + (size_t)vt_ * 64 + vdq * 8);

    for (int j = 0; j <= jn; ++j) {
      int kv0 = j * 64;
      const u16* ksb = Ks[j & 1];
      // write V^T tile j (swizzled; 2-way max bank aliasing)
#pragma unroll
      for (int jj = 0; jj < 8; ++jj) {
        int d = vdq * 8 + jj;
        Vt[d * 64 + (((vt_ >> 3) ^ jj ^ vdq) << 3) + (vt_ & 7)] = va[jj];
      }
      __syncthreads();  // [A] K(j) landed (vmcnt drain), Vt visible

      if (j < jn) {  // prefetch next tile
        int kv1 = kv0 + 64;
        GLD16(Kb + (size_t)(kv1 + kr) * 64 + ((ks8 ^ (kr & 7)) << 3),
              &Ks[(j + 1) & 1][0] + w * 512);
        va = *(const u16x8*)(Vb + (size_t)(kv1 + vt_) * 64 + vdq * 8);
      }

      bool active = kv0 <= q0w + 31;
      if (active) {
        int qg = q0w + l31;
        bf16x8 kf[2][4];
#pragma unroll
        for (int kt = 0; kt < 2; ++kt)
#pragma unroll
          for (int ds = 0; ds < 4; ++ds)
            kf[kt][ds] = *(const bf16x8*)&ksb[(32 * kt + l31) * 64 +
                                              (((2 * ds + hi) ^ l7) << 3)];
        // QK^T swapped: S^T[k][q]; lane col=q=l31, k rows=crow(r,hi)
        f32x16 sa[2];
        __builtin_amdgcn_s_setprio(1);
#pragma unroll
        for (int kt = 0; kt < 2; ++kt) {
          f32x16 acc;
#pragma unroll
          for (int r = 0; r < 16; ++r) acc[r] = 0.f;
#pragma unroll
          for (int ds = 0; ds < 4; ++ds)
            acc = __builtin_amdgcn_mfma_f32_32x32x16_bf16(kf[kt][ds], qreg[ds],
                                                          acc, 0, 0, 0);
          sa[kt] = acc;
        }
        __builtin_amdgcn_s_setprio(0);

        float mloc = -3e38f;
        if (kv0 + 63 > q0w) {  // masking tile
#pragma unroll
          for (int kt = 0; kt < 2; ++kt)
#pragma unroll
            for (int r = 0; r < 16; ++r) {
              int kg = kv0 + kt * 32 + ((r & 3) + 8 * (r >> 2) + 4 * hi);
              float v = sa[kt][r];
              v = (kg <= qg) ? v : -8e30f;
              sa[kt][r] = v;
              mloc = fmaxf(mloc, v);
            }
        } else {
#pragma unroll
          for (int kt = 0; kt < 2; ++kt)
#pragma unroll
            for (int r = 0; r < 16; ++r) mloc = fmaxf(mloc, sa[kt][r]);
        }
        float mx = fmaxf(mloc, __shfl_xor(mloc, 32)) * 0.125f;
        if (!__all(mx <= m_run + 8.f)) {  // defer-max (T13)
          float mn = fmaxf(m_run, mx);
          float fsc = __expf(m_run - mn);
          m_run = mn;
          l_run *= fsc;
#pragma unroll
          for (int r = 0; r < 16; ++r) {
            float fv = __shfl(fsc, (r & 3) + 8 * (r >> 2) + 4 * hi + 32 * hi);
            o_acc[0][r] *= fv;
            o_acc[1][r] *= fv;
          }
        }
        // p = exp2(s*0.125*log2e - m*log2e)
        float mm = m_run * 1.44269504f;
        float lloc = 0.f;
#pragma unroll
        for (int kt = 0; kt < 2; ++kt)
#pragma unroll
          for (int r = 0; r < 16; ++r) {
            float p = exp2f(__builtin_fmaf(sa[kt][r], 0.18033688f, -mm));
            sa[kt][r] = p;
            lloc += p;
          }
        l_run += lloc + __shfl_xor(lloc, 32);
        // pack P to bf16 pairs (1 cvt_pk each)
        unsigned pk0[8], pk1[8];
#pragma unroll
        for (int m = 0; m < 8; ++m) {
          pk0[m] = cvt_pk_bf16(sa[0][2 * m], sa[0][2 * m + 1]);
          pk1[m] = cvt_pk_bf16(sa[1][2 * m], sa[1][2 * m + 1]);
        }
        // V^T fragments (loaded late to bound live VGPRs)
        bf16x8 vf[2][4];
#pragma unroll
        for (int dt = 0; dt < 2; ++dt)
#pragma unroll
          for (int ks = 0; ks < 4; ++ks) {
            int d = 32 * dt + l31;
            int ch = ((2 * ks + hi) ^ (d & 7) ^ ((d >> 3) & 7)) & 7;
            vf[dt][ks] = *(const bf16x8*)&Vt[d * 64 + (ch << 3)];
          }
        // build PV A-frags via one shfl_xor(32) pair per kstep (verified R4 form)
#pragma unroll
        for (int ks = 0; ks < 4; ++ks) {
          int c0 = 4 * (ks & 1);
          unsigned a0 = (ks < 2) ? pk0[c0] : pk1[c0];
          unsigned a1 = (ks < 2) ? pk0[c0 + 1] : pk1[c0 + 1];
          unsigned a2 = (ks < 2) ? pk0[c0 + 2] : pk1[c0 + 2];
          unsigned a3 = (ks < 2) ? pk0[c0 + 3] : pk1[c0 + 3];
          unsigned pubX = hi ? a0 : a2;
          unsigned pubY = hi ? a1 : a3;
          unsigned rx = (unsigned)__shfl_xor((int)pubX, 32);
          unsigned ry = (unsigned)__shfl_xor((int)pubY, 32);
          u32x4 fa;
          fa.x = hi ? rx : a0;
          fa.y = hi ? ry : a1;
          fa.z = hi ? a2 : rx;
          fa.w = hi ? a3 : ry;
          bf16x8 paf = __builtin_bit_cast(bf16x8, fa);
          __builtin_amdgcn_s_setprio(1);
#pragma unroll
          for (int dt = 0; dt < 2; ++dt)
            o_acc[dt] = __builtin_amdgcn_mfma_f32_32x32x16_bf16(
                paf, vf[dt][ks], o_acc[dt], 0, 0, 0);
          __builtin_amdgcn_s_setprio(0);
        }
      }
      __syncthreads();  // [B] Ks(j)/Vt reads done before next tile's writes
    }

    // epilogue: normalize and store
#pragma unroll
    for (int r = 0; r < 16; ++r) {
      int crow = (r & 3) + 8 * (r >> 2) + 4 * hi;
      float li = __shfl(l_run, crow + 32 * hi);
      float inv = 1.f / li;
      int q = q0w + crow;
#pragma unroll
      for (int dt = 0; dt < 2; ++dt) {
        float y = o_acc[dt][r] * inv;
        Yg[(size_t)(b * 2048 + q) * 1024 + h * 64 + dt * 32 + l31] = f2bf(y);
      }
    }
  }
}

// ---------------- launch ----------------

extern "C" void kernel_launch(void* const* d_in, const int* in_sizes, int n_in,
                              void* d_out, int out_size, void* d_ws, size_t ws_size,
                              hipStream_t stream) {
  const float* x = (const float*)d_in[0];
  const float* w_qkv = (const float*)d_in[1];
  const float* w_proj = (const float*)d_in[2];
  float* out = (float*)d_out;
  u16* ws = (u16*)d_ws;

  u16* xb = ws;                  // 8388608 elems (B*T*C)
  u16* wq = xb + 8388608;        // 3145728 (3C x C, transposed)
  u16* wp = wq + 3145728;        // 1048576 (C x C, transposed)
  u16* Qb = wp + 1048576;        // 8388608 each, [B,H,T,D]
  u16* Kb = Qb + 8388608;
  u16* Vb = Kb + 8388608;
  u16* Yb = xb;                  // alias: x_bf16 dead after QKV GEMM

  cast_f32_bf16<<<8192, 256, 0, stream>>>(x, xb, 2097152);
  transpose_cast<<<dim3(96, 32), dim3(32, 8), 0, stream>>>(w_qkv, wq, 1024, 3072);
  transpose_cast<<<dim3(32, 32), dim3(32, 8), 0, stream>>>(w_proj, wp, 1024, 1024);
  gemm_bt<0><<<dim3(24, 64), 256, 0, stream>>>(xb, wq, 1024, Qb, Kb, Vb, nullptr, 3072);
  attn_fwd<<<256, 512, 0, stream>>>(Qb, Kb, Vb, Yb);
  gemm_bt<1><<<dim3(8, 64), 256, 0, stream>>>(Yb, wp, 1024, nullptr, nullptr, nullptr, out, 1024);
}